// Round 8
// baseline (444.118 us; speedup 1.0000x reference)
//
#include <hip/hip_runtime.h>
#include <stdint.h>

#define NN 50000
#define NE 800000
#define NG 256
#define NBUCKET 16
#define PARTSZ (NBUCKET * 256)

// bucketed CSR build params
#define NBKT 391      // node buckets of 128
#define ABLK 391
#define ASLICE 2048
#define BCAP 2560

#define AFF4(u, sc, sh) { u.x = fmaxf(sc.x*u.x+sh.x,0.f); u.y = fmaxf(sc.y*u.y+sh.y,0.f); \
                          u.z = fmaxf(sc.z*u.z+sh.z,0.f); u.w = fmaxf(sc.w*u.w+sh.w,0.f); }

// BN coefficients from double-precision partial sums (replay-stable)
__device__ __forceinline__ void bn_coef(const double* __restrict__ partIn,
                                        const float* __restrict__ gmv,
                                        const float* __restrict__ btv,
                                        int tid, int n, float* scs, float* shs) {
    double s = 0., q = 0.;
#pragma unroll
    for (int b2 = 0; b2 < NBUCKET; ++b2) {
        s += partIn[b2 * 256 + tid];
        q += partIn[b2 * 256 + 128 + tid];
    }
    double mu = s / (double)n;
    double var = q / (double)n - mu * mu;
    float a = gmv[tid] * rsqrtf((float)var + 1e-5f);
    scs[tid] = a;
    shs[tid] = btv[tid] - (float)mu * a;
}

// wave-parallel exclusive scan of totals[0..NBKT) into sbase[0..NBKT] (sbase[NBKT]=sum)
__device__ __forceinline__ void scan_totals(const int* __restrict__ totals,
                                            int* __restrict__ sbase, int tid) {
    if (tid < 64) {
        const int C = (NBKT + 63) / 64;  // 7
        int tv[C];
        int s = 0;
        int i0 = tid * C;
#pragma unroll
        for (int j = 0; j < C; ++j) {
            int idx = i0 + j;
            int x = (idx < NBKT) ? totals[idx] : 0;
            tv[j] = x; s += x;
        }
        int inc = s;
        for (int off = 1; off < 64; off <<= 1) {
            int t2 = __shfl_up(inc, off, 64);
            if (tid >= off) inc += t2;
        }
        int run = inc - s;
#pragma unroll
        for (int j = 0; j < C; ++j) {
            int idx = i0 + j;
            if (idx < NBKT) sbase[idx] = run;
            run += tv[j];
        }
        if (tid == 63) sbase[NBKT] = run;
    }
}

// ---------------- prologue ----------------
__global__ void kA1(const int* __restrict__ col, int* __restrict__ bb,
                    double* __restrict__ zz, int zn, int e) {
    __shared__ int cnt[NBKT];
    for (int j = threadIdx.x; j < NBKT; j += 256) cnt[j] = 0;
    for (int i = blockIdx.x * 256 + threadIdx.x; i < zn; i += ABLK * 256) zz[i] = 0.;
    __syncthreads();
    int start = blockIdx.x * ASLICE;
    int end = min(start + ASLICE, e);
    for (int i = start + threadIdx.x; i < end; i += 256)
        atomicAdd(&cnt[col[i] >> 7], 1);
    __syncthreads();
    for (int j = threadIdx.x; j < NBKT; j += 256) bb[blockIdx.x * NBKT + j] = cnt[j];
}

__global__ void kA2a(int* __restrict__ bb, int* __restrict__ totals) {
    __shared__ int v[ABLK];
    int k = blockIdx.x;
    int tid = threadIdx.x;
    for (int b = tid; b < ABLK; b += 256) v[b] = bb[b * NBKT + k];
    __syncthreads();
    if (tid < 64) {
        const int C = (ABLK + 63) / 64;  // 7
        int tv[C];
        int s = 0;
        int i0 = tid * C;
#pragma unroll
        for (int j = 0; j < C; ++j) {
            int idx = i0 + j;
            int x = (idx < ABLK) ? v[idx] : 0;
            tv[j] = x; s += x;
        }
        int inc = s;
        for (int off = 1; off < 64; off <<= 1) {
            int t2 = __shfl_up(inc, off, 64);
            if (tid >= off) inc += t2;
        }
        int run = inc - s;
#pragma unroll
        for (int j = 0; j < C; ++j) {
            int idx = i0 + j;
            if (idx < ABLK) v[idx] = run;
            run += tv[j];
        }
        if (tid == 63) totals[k] = run;
    }
    __syncthreads();
    for (int b = tid; b < ABLK; b += 256) bb[b * NBKT + k] = v[b];
}

// A3 (blocks [0,ABLK)) + independent L1 gemm 128->16 (blocks [ABLK,..)) in one dispatch
__global__ void kA3g(const int* __restrict__ row, const int* __restrict__ col,
                     const float* __restrict__ ew, const int* __restrict__ bb,
                     const int* __restrict__ totals, int2* __restrict__ staging,
                     const float* __restrict__ x, const float* __restrict__ W0,
                     float* __restrict__ m1, int e, int n) {
    __shared__ int cur[NBKT];
    __shared__ int sbase[NBKT + 1];
    __shared__ float Wl[128 * 16];
    int tid = threadIdx.x;
    if ((int)blockIdx.x < ABLK) {
        scan_totals(totals, sbase, tid);
        __syncthreads();
        for (int j = tid; j < NBKT; j += 256)
            cur[j] = sbase[j] + bb[blockIdx.x * NBKT + j];
        __syncthreads();
        int start = blockIdx.x * ASLICE;
        int end = min(start + ASLICE, e);
        for (int i = start + tid; i < end; i += 256) {
            int c = col[i];
            int p = atomicAdd(&cur[c >> 7], 1);
            staging[p] = make_int2(row[i] | ((c & 127) << 16), __float_as_int(ew[i]));
        }
        return;
    }
    int bid = (int)blockIdx.x - ABLK;
    for (int i = tid; i < 128 * 16 / 4; i += 256)
        ((float4*)Wl)[i] = ((const float4*)W0)[i];
    __syncthreads();
    int jq = tid % 4, group = tid / 4;
    int node0 = (bid * 64 + group) * 2;
    const float4* h4 = (const float4*)x;
    int hb[2]; bool val[2];
#pragma unroll
    for (int i = 0; i < 2; ++i) {
        int nd = node0 + i;
        val[i] = nd < n;
        hb[i] = (val[i] ? nd : n - 1) * 32;
    }
    float4 acc[2];
    acc[0] = {0,0,0,0}; acc[1] = {0,0,0,0};
#pragma unroll 4
    for (int k4 = 0; k4 < 32; ++k4) {
        const float* wb = &Wl[(k4 * 4) * 16 + jq * 4];
        float4 w0 = *(const float4*)(wb);
        float4 w1 = *(const float4*)(wb + 16);
        float4 w2 = *(const float4*)(wb + 32);
        float4 w3 = *(const float4*)(wb + 48);
#pragma unroll
        for (int i = 0; i < 2; ++i) {
            float4 hv = h4[hb[i] + k4];
            acc[i].x += hv.x*w0.x + hv.y*w1.x + hv.z*w2.x + hv.w*w3.x;
            acc[i].y += hv.x*w0.y + hv.y*w1.y + hv.z*w2.y + hv.w*w3.y;
            acc[i].z += hv.x*w0.z + hv.y*w1.z + hv.z*w2.z + hv.w*w3.z;
            acc[i].w += hv.x*w0.w + hv.y*w1.w + hv.z*w2.w + hv.w*w3.w;
        }
    }
#pragma unroll
    for (int i = 0; i < 2; ++i)
        if (val[i]) ((float4*)m1)[(node0 + i) * 4 + jq] = acc[i];
}

// kB: counting-sort by dest node, then DETERMINISTIC per-node insertion sort by
// (src id, weight bits) — canonicalizes the atomic scatter order so every
// downstream fp32 accumulation runs in a fixed order (replay-stable).
// csr entry: .x = src node id, .y = fp32 weight bits.
__global__ void __launch_bounds__(256) kB(const int* __restrict__ totals,
                                          const int2* __restrict__ staging,
                                          int2* __restrict__ csr, int* __restrict__ ptr,
                                          float* __restrict__ dis, int n) {
    __shared__ int2 st[BCAP];
    __shared__ int2 outb[BCAP];
    __shared__ int hist[129];
    __shared__ int cur[128];
    __shared__ int sbase[NBKT + 1];
    int k = blockIdx.x, t = threadIdx.x;
    scan_totals(totals, sbase, t);
    if (t < 129) hist[t] = 0;
    __syncthreads();
    int base = sbase[k], cnt = sbase[k + 1] - sbase[k];
    int node0 = k << 7;
    int ncov = min(128, n - node0);
    if (cnt <= BCAP) {
        for (int i = t; i < cnt; i += 256) {
            int2 v = staging[base + i];
            st[i] = v;
            atomicAdd(&hist[v.x >> 16], 1);
        }
        __syncthreads();
        if (t == 0) {
            int run = 0;
            for (int j = 0; j < 128; ++j) { int h = hist[j]; hist[j] = run; run += h; }
            hist[128] = run;
        }
        __syncthreads();
        if (t < 128) cur[t] = hist[t];
        if (t < ncov) ptr[node0 + t] = base + hist[t];
        __syncthreads();
        for (int i = t; i < cnt; i += 256) {
            int2 v = st[i];
            int j = v.x >> 16;
            int p = atomicAdd(&cur[j], 1);
            outb[p] = make_int2(v.x & 0xFFFF, v.y);
        }
        __syncthreads();
        if (t < ncov) {
            int a0 = hist[t], b2 = hist[t + 1];
            for (int i = a0 + 1; i < b2; ++i) {
                int2 key = outb[i];
                int j = i - 1;
                while (j >= a0) {
                    int2 cj = outb[j];
                    if (cj.x > key.x || (cj.x == key.x && (unsigned)cj.y > (unsigned)key.y)) {
                        outb[j + 1] = cj; --j;
                    } else break;
                }
                outb[j + 1] = key;
            }
            float s = 1.f;
            for (int p = a0; p < b2; ++p) s += __int_as_float(outb[p].y);
            dis[node0 + t] = rsqrtf(s);
        }
        __syncthreads();
        for (int i = t; i < cnt; i += 256) csr[base + i] = outb[i];
    } else {
        for (int i = t; i < cnt; i += 256) atomicAdd(&hist[staging[base + i].x >> 16], 1);
        __syncthreads();
        if (t == 0) {
            int run = 0;
            for (int j = 0; j < 128; ++j) { int h = hist[j]; hist[j] = run; run += h; }
            hist[128] = run;
        }
        __syncthreads();
        if (t < 128) cur[t] = hist[t];
        if (t < ncov) ptr[node0 + t] = base + hist[t];
        __syncthreads();
        for (int i = t; i < cnt; i += 256) {
            int2 v = staging[base + i];
            int j = v.x >> 16;
            int p = atomicAdd(&cur[j], 1);
            csr[base + p] = make_int2(v.x & 0xFFFF, v.y);
        }
        __threadfence_block();
        __syncthreads();
        if (t < ncov) {
            int a0 = base + hist[t], b2 = base + hist[t + 1];
            for (int i = a0 + 1; i < b2; ++i) {
                int2 key = csr[i];
                int j = i - 1;
                while (j >= a0) {
                    int2 cj = csr[j];
                    if (cj.x > key.x || (cj.x == key.x && (unsigned)cj.y > (unsigned)key.y)) {
                        csr[j + 1] = cj; --j;
                    } else break;
                }
                csr[j + 1] = key;
            }
            float s = 1.f;
            for (int p = a0; p < b2; ++p) s += __int_as_float(csr[p].y);
            dis[node0 + t] = rsqrtf(s);
        }
    }
    if (k == gridDim.x - 1 && t == 0) ptr[n] = sbase[NBKT];
}

// ---------------- L1 gather: fp32 acc (deterministic CSR order), EPI + CSR rescale -------
__global__ void k_l1gather(const float* __restrict__ src, const int* __restrict__ ptr,
                           int2* __restrict__ csr, const float* __restrict__ dis,
                           const float* __restrict__ bias, double* __restrict__ partOut,
                           float* __restrict__ out, int n) {
    int tid = threadIdx.x;
    int t = blockIdx.x * 256 + tid;
    int node = t >> 2;
    int l4 = t & 3;
    bool valid = node < n;
    int nc = valid ? node : n - 1;
    const float4* s4 = (const float4*)src;
    float dc = dis[nc];
    float w0 = dc * dc;
    float4 v = s4[nc * 4 + l4];
    float4 acc = { w0 * v.x, w0 * v.y, w0 * v.z, w0 * v.w };
    int p0 = ptr[nc], p1 = ptr[nc + 1];
    int p = p0;
    for (; p + 4 <= p1; p += 4) {
        int2 c0 = csr[p], c1 = csr[p+1], c2 = csr[p+2], c3 = csr[p+3];
        float e0 = dis[c0.x] * __int_as_float(c0.y) * dc;
        float e1 = dis[c1.x] * __int_as_float(c1.y) * dc;
        float e2 = dis[c2.x] * __int_as_float(c2.y) * dc;
        float e3 = dis[c3.x] * __int_as_float(c3.y) * dc;
        float4 u0 = s4[c0.x * 4 + l4];
        float4 u1 = s4[c1.x * 4 + l4];
        float4 u2 = s4[c2.x * 4 + l4];
        float4 u3 = s4[c3.x * 4 + l4];
        acc.x += e0*u0.x + e1*u1.x + e2*u2.x + e3*u3.x;
        acc.y += e0*u0.y + e1*u1.y + e2*u2.y + e3*u3.y;
        acc.z += e0*u0.z + e1*u1.z + e2*u2.z + e3*u3.z;
        acc.w += e0*u0.w + e1*u1.w + e2*u2.w + e3*u3.w;
        if (l4 == 0) {
            csr[p]   = make_int2(c0.x, __float_as_int(e0));
            csr[p+1] = make_int2(c1.x, __float_as_int(e1));
            csr[p+2] = make_int2(c2.x, __float_as_int(e2));
            csr[p+3] = make_int2(c3.x, __float_as_int(e3));
        }
    }
    for (; p < p1; ++p) {
        int2 ce = csr[p];
        float w = dis[ce.x] * __int_as_float(ce.y) * dc;
        float4 u = s4[ce.x * 4 + l4];
        acc.x += w*u.x; acc.y += w*u.y; acc.z += w*u.z; acc.w += w*u.w;
        if (l4 == 0) csr[p] = make_int2(ce.x, __float_as_int(w));
    }
    float4 b = ((const float4*)bias)[l4];
    acc.x = fmaxf(acc.x + b.x, 0.f);
    acc.y = fmaxf(acc.y + b.y, 0.f);
    acc.z = fmaxf(acc.z + b.z, 0.f);
    acc.w = fmaxf(acc.w + b.w, 0.f);
    if (valid) ((float4*)out)[nc * 4 + l4] = acc;
    float s0 = valid ? acc.x : 0.f, s1 = valid ? acc.y : 0.f;
    float s2 = valid ? acc.z : 0.f, s3 = valid ? acc.w : 0.f;
    float q0 = s0*s0, q1 = s1*s1, q2 = s2*s2, q3 = s3*s3;
    for (int off = 4; off < 64; off <<= 1) {
        s0 += __shfl_down(s0, off, 64); s1 += __shfl_down(s1, off, 64);
        s2 += __shfl_down(s2, off, 64); s3 += __shfl_down(s3, off, 64);
        q0 += __shfl_down(q0, off, 64); q1 += __shfl_down(q1, off, 64);
        q2 += __shfl_down(q2, off, 64); q3 += __shfl_down(q3, off, 64);
    }
    int lane = tid & 63;
    int bkt = (blockIdx.x & (NBUCKET - 1)) * 256;
    if (lane < 4) {
        atomicAdd(&partOut[bkt + 4*lane + 0], (double)s0);
        atomicAdd(&partOut[bkt + 4*lane + 1], (double)s1);
        atomicAdd(&partOut[bkt + 4*lane + 2], (double)s2);
        atomicAdd(&partOut[bkt + 4*lane + 3], (double)s3);
        atomicAdd(&partOut[bkt + 128 + 4*lane + 0], (double)q0);
        atomicAdd(&partOut[bkt + 128 + 4*lane + 1], (double)q1);
        atomicAdd(&partOut[bkt + 128 + 4*lane + 2], (double)q2);
        atomicAdd(&partOut[bkt + 128 + 4*lane + 3], (double)q3);
    }
}

// ---------------- fused layer F2 (16->32): fp32 gather -> LDS rows -> gemm ---------------
template <int DIN, int DOUT, int EP, int RELU, int NPB>
__global__ void __launch_bounds__(256) k_fused(
        const float* __restrict__ src, const int* __restrict__ ptr,
        const int2* __restrict__ csr, const float* __restrict__ dis,
        const double* __restrict__ partIn, const float* __restrict__ gmv,
        const float* __restrict__ btv, const float* __restrict__ W,
        const float* __restrict__ bias, double* __restrict__ partOut,
        float* __restrict__ out, int n) {
    const int TPN1 = DIN / 4, LPN = TPN1 * EP, GN1 = 256 / LPN;
    const int TPN2 = DOUT / 4, G2 = 256 / TPN2;
    const int HS = DIN + 4;
    __shared__ float Wl[DIN * DOUT];
    __shared__ float hrow[NPB * HS];
    __shared__ float scs[DIN], shs[DIN];
    __shared__ double ls[DOUT], lq[DOUT];
    int tid = threadIdx.x;
    for (int i = tid; i < DIN * DOUT / 4; i += 256)
        ((float4*)Wl)[i] = ((const float4*)W)[i];
    if (tid < DIN) bn_coef(partIn, gmv, btv, tid, n, scs, shs);
    if (tid < DOUT) { ls[tid] = 0.; lq[tid] = 0.; }
    __syncthreads();

    int nodebase = blockIdx.x * NPB;
    {
        int grp = tid / LPN, r = tid % LPN;
        int e0 = r / TPN1, l4 = r % TPN1;
        float4 sc = ((const float4*)scs)[l4];
        float4 sh = ((const float4*)shs)[l4];
        const float4* s4 = (const float4*)src;
#pragma unroll
        for (int pass = 0; pass < NPB / GN1; ++pass) {
            int nl = pass * GN1 + grp;
            int node = nodebase + nl;
            int nc = node < n ? node : n - 1;
            float4 acc = {0.f, 0.f, 0.f, 0.f};
            float sumw = 0.f;
            if (e0 == 0) {
                float d = dis[nc];
                float w0 = d * d;
                float4 v = s4[(size_t)nc * TPN1 + l4];
                acc.x = w0*v.x; acc.y = w0*v.y; acc.z = w0*v.z; acc.w = w0*v.w;
                sumw = w0;
            }
            int p0 = ptr[nc], p1 = ptr[nc + 1];
            int p = p0 + e0;
            for (; p + 3 * EP < p1; p += 4 * EP) {
                int2 c0 = csr[p], c1 = csr[p + EP], c2 = csr[p + 2*EP], c3 = csr[p + 3*EP];
                float e0w = __int_as_float(c0.y), e1w = __int_as_float(c1.y);
                float e2w = __int_as_float(c2.y), e3w = __int_as_float(c3.y);
                float4 u0 = s4[(size_t)c0.x * TPN1 + l4];
                float4 u1 = s4[(size_t)c1.x * TPN1 + l4];
                float4 u2 = s4[(size_t)c2.x * TPN1 + l4];
                float4 u3 = s4[(size_t)c3.x * TPN1 + l4];
                acc.x += e0w*u0.x + e1w*u1.x + e2w*u2.x + e3w*u3.x;
                acc.y += e0w*u0.y + e1w*u1.y + e2w*u2.y + e3w*u3.y;
                acc.z += e0w*u0.z + e1w*u1.z + e2w*u2.z + e3w*u3.z;
                acc.w += e0w*u0.w + e1w*u1.w + e2w*u2.w + e3w*u3.w;
                sumw += e0w + e1w + e2w + e3w;
            }
            for (; p < p1; p += EP) {
                int2 ce = csr[p];
                float w = __int_as_float(ce.y);
                float4 u = s4[(size_t)ce.x * TPN1 + l4];
                acc.x += w*u.x; acc.y += w*u.y; acc.z += w*u.z; acc.w += w*u.w;
                sumw += w;
            }
#pragma unroll
            for (int off = TPN1; off < LPN; off <<= 1) {
                acc.x += __shfl_xor(acc.x, off, 64);
                acc.y += __shfl_xor(acc.y, off, 64);
                acc.z += __shfl_xor(acc.z, off, 64);
                acc.w += __shfl_xor(acc.w, off, 64);
                sumw += __shfl_xor(sumw, off, 64);
            }
            if (e0 == 0) {
                float4 o;
                o.x = sc.x * acc.x + sh.x * sumw;
                o.y = sc.y * acc.y + sh.y * sumw;
                o.z = sc.z * acc.z + sh.z * sumw;
                o.w = sc.w * acc.w + sh.w * sumw;
                *(float4*)&hrow[nl * HS + (l4 << 2)] = o;
            }
        }
    }
    __syncthreads();
    {
        int jq = tid % TPN2, g2 = tid / TPN2;
        float4 bv = ((const float4*)bias)[jq];
        float4 sv = {0,0,0,0}, qv = {0,0,0,0};
        for (int nl = g2; nl < NPB; nl += G2) {
            int node = nodebase + nl;
            bool valid = node < n;
            float4 a = {0.f, 0.f, 0.f, 0.f};
#pragma unroll
            for (int k4 = 0; k4 < DIN / 4; ++k4) {
                float4 hv = *(const float4*)&hrow[nl * HS + (k4 << 2)];
                const float* wb = &Wl[(k4 * 4) * DOUT + jq * 4];
                float4 w0 = *(const float4*)(wb);
                float4 w1 = *(const float4*)(wb + DOUT);
                float4 w2 = *(const float4*)(wb + 2 * DOUT);
                float4 w3 = *(const float4*)(wb + 3 * DOUT);
                a.x += hv.x*w0.x + hv.y*w1.x + hv.z*w2.x + hv.w*w3.x;
                a.y += hv.x*w0.y + hv.y*w1.y + hv.z*w2.y + hv.w*w3.y;
                a.z += hv.x*w0.z + hv.y*w1.z + hv.z*w2.z + hv.w*w3.z;
                a.w += hv.x*w0.w + hv.y*w1.w + hv.z*w2.w + hv.w*w3.w;
            }
            a.x += bv.x; a.y += bv.y; a.z += bv.z; a.w += bv.w;
            if (RELU) {
                a.x = fmaxf(a.x, 0.f); a.y = fmaxf(a.y, 0.f);
                a.z = fmaxf(a.z, 0.f); a.w = fmaxf(a.w, 0.f);
            }
            if (valid) {
                ((float4*)out)[(size_t)node * TPN2 + jq] = a;
                sv.x += a.x; sv.y += a.y; sv.z += a.z; sv.w += a.w;
                qv.x += a.x*a.x; qv.y += a.y*a.y; qv.z += a.z*a.z; qv.w += a.w*a.w;
            }
        }
        for (int off = TPN2; off < 64; off <<= 1) {
            sv.x += __shfl_down(sv.x, off, 64); sv.y += __shfl_down(sv.y, off, 64);
            sv.z += __shfl_down(sv.z, off, 64); sv.w += __shfl_down(sv.w, off, 64);
            qv.x += __shfl_down(qv.x, off, 64); qv.y += __shfl_down(qv.y, off, 64);
            qv.z += __shfl_down(qv.z, off, 64); qv.w += __shfl_down(qv.w, off, 64);
        }
        int lane = tid & 63;
        if (lane < TPN2) {
            atomicAdd(&ls[4*lane+0], (double)sv.x); atomicAdd(&ls[4*lane+1], (double)sv.y);
            atomicAdd(&ls[4*lane+2], (double)sv.z); atomicAdd(&ls[4*lane+3], (double)sv.w);
            atomicAdd(&lq[4*lane+0], (double)qv.x); atomicAdd(&lq[4*lane+1], (double)qv.y);
            atomicAdd(&lq[4*lane+2], (double)qv.z); atomicAdd(&lq[4*lane+3], (double)qv.w);
        }
        __syncthreads();
        int bkt = (blockIdx.x & (NBUCKET - 1)) * 256;
        if (tid < DOUT) {
            atomicAdd(&partOut[bkt + tid], ls[tid]);
            atomicAdd(&partOut[bkt + 128 + tid], lq[tid]);
        }
    }
}

// ---------------- wide standalone gather (L3/L4/L5): fp32 rows, fp32 acc -----------------
template <int D, int POSTAFF, int PREAFF>
__global__ void __launch_bounds__(256) k_wgather(
        const float* __restrict__ src, const int* __restrict__ ptr,
        const int2* __restrict__ csr, const float* __restrict__ dis,
        const double* __restrict__ partIn, const float* __restrict__ gmv,
        const float* __restrict__ btv, float* __restrict__ out, int n) {
    const int RL = D / 4;          // lanes per row (float4 each)
    const int EP = 4;
    const int LPN = RL * EP;
    __shared__ float scs[D], shs[D];
    int tid = threadIdx.x;
    if (tid < D) bn_coef(partIn, gmv, btv, tid, n, scs, shs);
    __syncthreads();
    int t = blockIdx.x * 256 + tid;
    int node = t / LPN;
    int r = t - node * LPN;
    int e0 = r / RL;
    int l4 = r - e0 * RL;
    bool valid = node < n;
    int nc = valid ? node : n - 1;
    const float4* s4 = (const float4*)src;
    float4 sc = ((const float4*)scs)[l4], sh = ((const float4*)shs)[l4];
    float4 acc = {0.f, 0.f, 0.f, 0.f};
    float sumw = 0.f;
    if (e0 == 0) {
        float d = dis[nc];
        float w0 = d * d;
        float4 v = s4[(size_t)nc * RL + l4];
        if (PREAFF) AFF4(v, sc, sh);
        acc.x = w0*v.x; acc.y = w0*v.y; acc.z = w0*v.z; acc.w = w0*v.w;
        sumw = w0;
    }
    int p0 = ptr[nc], p1 = ptr[nc + 1];
    int p = p0 + e0;
    for (; p + 3 * EP < p1; p += 4 * EP) {
        int2 c0 = csr[p], c1 = csr[p + EP], c2 = csr[p + 2*EP], c3 = csr[p + 3*EP];
        float w0 = __int_as_float(c0.y), w1 = __int_as_float(c1.y);
        float w2 = __int_as_float(c2.y), w3 = __int_as_float(c3.y);
        float4 u0 = s4[(size_t)c0.x * RL + l4];
        float4 u1 = s4[(size_t)c1.x * RL + l4];
        float4 u2 = s4[(size_t)c2.x * RL + l4];
        float4 u3 = s4[(size_t)c3.x * RL + l4];
        if (PREAFF) { AFF4(u0, sc, sh); AFF4(u1, sc, sh); AFF4(u2, sc, sh); AFF4(u3, sc, sh); }
        acc.x += w0*u0.x + w1*u1.x + w2*u2.x + w3*u3.x;
        acc.y += w0*u0.y + w1*u1.y + w2*u2.y + w3*u3.y;
        acc.z += w0*u0.z + w1*u1.z + w2*u2.z + w3*u3.z;
        acc.w += w0*u0.w + w1*u1.w + w2*u2.w + w3*u3.w;
        if (POSTAFF) sumw += w0 + w1 + w2 + w3;
    }
    for (; p < p1; p += EP) {
        int2 ce = csr[p];
        float w = __int_as_float(ce.y);
        float4 u = s4[(size_t)ce.x * RL + l4];
        if (PREAFF) AFF4(u, sc, sh);
        acc.x += w*u.x; acc.y += w*u.y; acc.z += w*u.z; acc.w += w*u.w;
        if (POSTAFF) sumw += w;
    }
#pragma unroll
    for (int off = RL; off < LPN; off <<= 1) {
        acc.x += __shfl_xor(acc.x, off, 64); acc.y += __shfl_xor(acc.y, off, 64);
        acc.z += __shfl_xor(acc.z, off, 64); acc.w += __shfl_xor(acc.w, off, 64);
        if (POSTAFF) sumw += __shfl_xor(sumw, off, 64);
    }
    if (valid && e0 == 0) {
        float4 o;
        if (POSTAFF) {
            o.x = sc.x * acc.x + sh.x * sumw;
            o.y = sc.y * acc.y + sh.y * sumw;
            o.z = sc.z * acc.z + sh.z * sumw;
            o.w = sc.w * acc.w + sh.w * sumw;
        } else {
            o = acc;
        }
        ((float4*)out)[(size_t)nc * RL + l4] = o;
    }
}

// ---------------- standalone gemm DIN -> DOUT, bias + optional relu + stats --------------
// POOL=1: accumulate group sums (double) into pooled[NG][DOUT] via LDS f64 aggregation.
template <int DIN, int DOUT, int RELU, int POOL>
__global__ void k_sgemm(const float* __restrict__ h, const float* __restrict__ W,
                        const float* __restrict__ bias, double* __restrict__ partOut,
                        float* __restrict__ m, const int* __restrict__ batch,
                        double* __restrict__ pooled, int n) {
    const int TPN = DOUT / 4, GPB = 256 / TPN, NPT = 4;
    const int NPBLK = GPB * NPT;
    const int MAXG = 34;
    __shared__ float Wl[DIN * DOUT];
    __shared__ double ls[DOUT], lq[DOUT];
    __shared__ double pool_l[POOL ? MAXG * DOUT : 1];
    __shared__ int gmaxs;
    int tid = threadIdx.x;
    for (int i = tid; i < DIN * DOUT / 4; i += 256)
        ((float4*)Wl)[i] = ((const float4*)W)[i];
    if (tid < DOUT) { ls[tid] = 0.; lq[tid] = 0.; }
    int gbase = 0;
    if (POOL) {
        for (int i = tid; i < MAXG * DOUT; i += 256) pool_l[i] = 0.;
        if (tid == 0) gmaxs = 0;
        int bn0 = blockIdx.x * NPBLK;
        gbase = batch[bn0 < n ? bn0 : n - 1];
    }
    __syncthreads();

    int jq = tid % TPN;
    int group = tid / TPN;
    int node0 = (blockIdx.x * GPB + group) * NPT;
    const float4* h4 = (const float4*)h;
    int hb[NPT]; bool val[NPT];
#pragma unroll
    for (int i = 0; i < NPT; ++i) {
        int nd = node0 + i;
        val[i] = nd < n;
        hb[i] = (val[i] ? nd : n - 1) * (DIN / 4);
    }
    float4 acc[NPT];
#pragma unroll
    for (int i = 0; i < NPT; ++i) acc[i] = {0.f, 0.f, 0.f, 0.f};
#pragma unroll 4
    for (int k4 = 0; k4 < DIN / 4; ++k4) {
        const float* wb = &Wl[(k4 * 4) * DOUT + jq * 4];
        float4 w0 = *(const float4*)(wb);
        float4 w1 = *(const float4*)(wb + DOUT);
        float4 w2 = *(const float4*)(wb + 2 * DOUT);
        float4 w3 = *(const float4*)(wb + 3 * DOUT);
#pragma unroll
        for (int i = 0; i < NPT; ++i) {
            float4 hv = h4[hb[i] + k4];
            acc[i].x += hv.x*w0.x + hv.y*w1.x + hv.z*w2.x + hv.w*w3.x;
            acc[i].y += hv.x*w0.y + hv.y*w1.y + hv.z*w2.y + hv.w*w3.y;
            acc[i].z += hv.x*w0.z + hv.y*w1.z + hv.z*w2.z + hv.w*w3.z;
            acc[i].w += hv.x*w0.w + hv.y*w1.w + hv.z*w2.w + hv.w*w3.w;
        }
    }
    float4 bv = ((const float4*)bias)[jq];
    float4 sv = {0,0,0,0}, qv = {0,0,0,0};
#pragma unroll
    for (int i = 0; i < NPT; ++i) {
        float4 a = acc[i];
        a.x += bv.x; a.y += bv.y; a.z += bv.z; a.w += bv.w;
        if (RELU) {
            a.x = fmaxf(a.x, 0.f); a.y = fmaxf(a.y, 0.f);
            a.z = fmaxf(a.z, 0.f); a.w = fmaxf(a.w, 0.f);
        }
        if (val[i]) {
            if (POOL) {
                int off = batch[node0 + i] - gbase;
                if (off < MAXG) {
                    atomicAdd(&pool_l[off * DOUT + jq * 4 + 0], (double)a.x);
                    atomicAdd(&pool_l[off * DOUT + jq * 4 + 1], (double)a.y);
                    atomicAdd(&pool_l[off * DOUT + jq * 4 + 2], (double)a.z);
                    atomicAdd(&pool_l[off * DOUT + jq * 4 + 3], (double)a.w);
                    if (jq == 0) atomicMax(&gmaxs, off);
                } else {
                    double* pg = &pooled[(size_t)(gbase + off) * DOUT + jq * 4];
                    atomicAdd(pg + 0, (double)a.x); atomicAdd(pg + 1, (double)a.y);
                    atomicAdd(pg + 2, (double)a.z); atomicAdd(pg + 3, (double)a.w);
                }
            } else {
                ((float4*)m)[(size_t)(node0 + i) * TPN + jq] = a;
            }
            sv.x += a.x; sv.y += a.y; sv.z += a.z; sv.w += a.w;
            qv.x += a.x*a.x; qv.y += a.y*a.y; qv.z += a.z*a.z; qv.w += a.w*a.w;
        }
    }
    for (int off = TPN; off < 64; off <<= 1) {
        sv.x += __shfl_down(sv.x, off, 64); sv.y += __shfl_down(sv.y, off, 64);
        sv.z += __shfl_down(sv.z, off, 64); sv.w += __shfl_down(sv.w, off, 64);
        qv.x += __shfl_down(qv.x, off, 64); qv.y += __shfl_down(qv.y, off, 64);
        qv.z += __shfl_down(qv.z, off, 64); qv.w += __shfl_down(qv.w, off, 64);
    }
    int lane = tid & 63;
    if (lane < TPN) {
        atomicAdd(&ls[4*lane+0], (double)sv.x); atomicAdd(&ls[4*lane+1], (double)sv.y);
        atomicAdd(&ls[4*lane+2], (double)sv.z); atomicAdd(&ls[4*lane+3], (double)sv.w);
        atomicAdd(&lq[4*lane+0], (double)qv.x); atomicAdd(&lq[4*lane+1], (double)qv.y);
        atomicAdd(&lq[4*lane+2], (double)qv.z); atomicAdd(&lq[4*lane+3], (double)qv.w);
    }
    __syncthreads();
    int bkt = (blockIdx.x & (NBUCKET - 1)) * 256;
    if (tid < DOUT) {
        atomicAdd(&partOut[bkt + tid], ls[tid]);
        atomicAdd(&partOut[bkt + 128 + tid], lq[tid]);
    }
    if (POOL) {
        int gm = gmaxs;
        for (int i = tid; i < (gm + 1) * DOUT; i += 256) {
            double v = pool_l[i];
            if (v != 0.) atomicAdd(&pooled[(size_t)gbase * DOUT + i], v);
        }
    }
}

// ---------------- pool head: BN5(from stats) applied to pooled sums + MLP ----------------
__global__ void __launch_bounds__(128) k_poolhead(
        const double* __restrict__ pooled, const int* __restrict__ batch,
        const double* __restrict__ partIn, const float* __restrict__ gmv,
        const float* __restrict__ btv,
        const float* __restrict__ fc1w, const float* __restrict__ fc1b,
        const float* __restrict__ fc2w, const float* __restrict__ fc2b,
        float* __restrict__ out, int n) {
    __shared__ float pl[128];
    __shared__ float scs[128], shs[128];
    int g = blockIdx.x;
    int tid = threadIdx.x;
    bn_coef(partIn, gmv, btv, tid, n, scs, shs);
    int a = 0, b = n;
    while (a < b) { int mid = (a + b) >> 1; if (batch[mid] < g) a = mid + 1; else b = mid; }
    int lo = a;
    b = n;
    while (a < b) { int mid = (a + b) >> 1; if (batch[mid] < g + 1) a = mid + 1; else b = mid; }
    int hi = a;
    float cntf = (float)(hi - lo);
    float p = scs[tid] * (float)pooled[g * 128 + tid] + shs[tid] * cntf;
    pl[tid] = fmaxf(p, 0.f);
    __syncthreads();
    if (tid < 64) {
        float v1 = fc1b[tid];
        for (int k = 0; k < 128; ++k) v1 += pl[k] * fc1w[k * 64 + tid];
        v1 = fmaxf(v1, 0.f);
        float v = v1 * fc2w[tid];
        for (int off = 32; off > 0; off >>= 1) v += __shfl_down(v, off, 64);
        if (tid == 0) out[g] = v + fc2b[0];
    }
}

// ---------------- driver ----------------
extern "C" void kernel_launch(void* const* d_in, const int* in_sizes, int n_in,
                              void* d_out, int out_size, void* d_ws, size_t ws_size,
                              hipStream_t stream) {
    const float* x     = (const float*)d_in[0];
    const int*   ei    = (const int*)d_in[1];
    const float* ew    = (const float*)d_in[2];
    const int*   batch = (const int*)d_in[3];
    const float *W[5], *b[5], *gm[5], *bt[5];
    for (int i = 0; i < 5; ++i) {
        W[i]  = (const float*)d_in[4 + 4 * i];
        b[i]  = (const float*)d_in[5 + 4 * i];
        gm[i] = (const float*)d_in[6 + 4 * i];
        bt[i] = (const float*)d_in[7 + 4 * i];
    }
    const float* fc1w = (const float*)d_in[24];
    const float* fc1b = (const float*)d_in[25];
    const float* fc2w = (const float*)d_in[26];
    const float* fc2b = (const float*)d_in[27];
    float* out = (float*)d_out;

    // workspace layout
    char* wsb = (char*)d_ws;
    float* dis    = (float*)wsb;  wsb += sizeof(float) * NN;
    int*   ptr    = (int*)wsb;    wsb += sizeof(int) * (NN + 4);
    int*   bb     = (int*)wsb;    wsb += sizeof(int) * ABLK * NBKT;
    int*   totals = (int*)wsb;    wsb += sizeof(int) * (NBKT + 1);
    wsb = (char*)(((uintptr_t)wsb + 15) & ~(uintptr_t)15);
    double* part   = (double*)wsb;  wsb += sizeof(double) * 5 * PARTSZ;
    double* pooled = (double*)wsb;  wsb += sizeof(double) * NG * 128;
    int2*  staging= (int2*)wsb;   wsb += sizeof(int2) * NE;
    int2*  csr    = (int2*)wsb;   wsb += sizeof(int2) * NE;
    float* bufB1  = (float*)wsb;  wsb += sizeof(float) * (size_t)NN * 64;
    float* bufB2  = (float*)wsb;  wsb += sizeof(float) * (size_t)NN * 64;
    float* buf1   = (float*)wsb;  wsb += sizeof(float) * (size_t)NN * 64;    // gathers / m1
    float* buf2   = (float*)wsb;  wsb += sizeof(float) * (size_t)NN * 16;    // L1 out

    const int* row = ei;
    const int* col = ei + NE;
    const int B = 256;
    const int NBF = (NN + 15) / 16;       // fused F2 blocks
    const int GB1 = (NN + 127) / 128;     // gemm1 blocks
    const int ZN = 5 * PARTSZ + NG * 128; // part+pooled zero region (contiguous doubles)

    // prologue: bucketed CSR build (deterministic via per-node sort in kB);
    // gemm1 overlapped with kA3 (independent work)
    kA1<<<ABLK, B, 0, stream>>>(col, bb, part, ZN, NE);
    kA2a<<<NBKT, B, 0, stream>>>(bb, totals);
    kA3g<<<ABLK + GB1, B, 0, stream>>>(row, col, ew, bb, totals, staging, x, W[0], buf1, NE, NN);
    kB<<<NBKT, B, 0, stream>>>(totals, staging, csr, ptr, dis, NN);

    // L1 gather (fp32 acc, deterministic order): bias+relu+stats + CSR rescale write-back
    k_l1gather<<<(NN * 4 + 255) / 256, B, 0, stream>>>(buf1, ptr, csr, dis,
                                                       b[0], part + 0 * PARTSZ, buf2, NN);

    // F2: 16->32 fused, consume part[0] (BN1 hoisted), fp32 in/out
    k_fused<16, 32, 4, 1, 16><<<NBF, B, 0, stream>>>(
        buf2, ptr, csr, dis, part + 0 * PARTSZ, gm[0], bt[0],
        W[1], b[1], part + 1 * PARTSZ, bufB1, NN);

    // L3: gather32 (BN2 hoisted) then gemm 32->64 (+relu)
    k_wgather<32, 1, 0><<<(int)(((long)NN * 32 + 255) / 256), B, 0, stream>>>(
        bufB1, ptr, csr, dis, part + 1 * PARTSZ, gm[1], bt[1], buf1, NN);
    k_sgemm<32, 64, 1, 0><<<(NN + 63) / 64, B, 0, stream>>>(
        buf1, W[2], b[2], part + 2 * PARTSZ, bufB2, nullptr, nullptr, NN);

    // L4: gather64 (BN3 hoisted) then gemm 64->64 (no relu; BN4 stats)
    k_wgather<64, 1, 0><<<(int)(((long)NN * 64 + 255) / 256), B, 0, stream>>>(
        bufB2, ptr, csr, dis, part + 2 * PARTSZ, gm[2], bt[2], buf1, NN);
    k_sgemm<64, 64, 0, 0><<<(NN + 63) / 64, B, 0, stream>>>(
        buf1, W[3], b[3], part + 3 * PARTSZ, bufB1, nullptr, nullptr, NN);

    // L5: gather64 (per-edge relu(BN4)) then gemm 64->128 fused with pool (f64 sums)
    k_wgather<64, 0, 1><<<(int)(((long)NN * 64 + 255) / 256), B, 0, stream>>>(
        bufB1, ptr, csr, dis, part + 3 * PARTSZ, gm[3], bt[3], buf1, NN);
    k_sgemm<64, 128, 0, 1><<<(NN + 31) / 32, B, 0, stream>>>(
        buf1, W[4], b[4], part + 4 * PARTSZ, nullptr, batch, pooled, NN);

    // head: BN5 (stats from part[4]) on pooled sums + MLP
    k_poolhead<<<NG, 128, 0, stream>>>(pooled, batch, part + 4 * PARTSZ, gm[4], bt[4],
                                       fc1w, fc1b, fc2w, fc2b, out, NN);
}